// Round 1
// baseline (1846.188 us; speedup 1.0000x reference)
//
#include <hip/hip_runtime.h>

#define N_NODES 200000
#define DIM 64
#define SCAN_CHUNK 2048

// ---- Pass 1: histogram of row degrees (counts in `cur`) ----
__global__ void hist_kernel(const int* __restrict__ rows, int E, int* __restrict__ counts) {
    int e = blockIdx.x * blockDim.x + threadIdx.x;
    if (e < E) atomicAdd(&counts[rows[e]], 1);
}

// ---- Pass 2a: per-chunk partial sums ----
__global__ void scan_partial(const int* __restrict__ counts, int n, int* __restrict__ chunkSum) {
    __shared__ int lds[256];
    int t = threadIdx.x;
    int base = blockIdx.x * SCAN_CHUNK + t * 8;
    int s = 0;
#pragma unroll
    for (int i = 0; i < 8; i++) { int idx = base + i; if (idx < n) s += counts[idx]; }
    lds[t] = s; __syncthreads();
    for (int off = 128; off > 0; off >>= 1) { if (t < off) lds[t] += lds[t + off]; __syncthreads(); }
    if (t == 0) chunkSum[blockIdx.x] = lds[0];
}

// ---- Pass 2b: exclusive scan of chunk sums (98 values; single thread is fine) ----
__global__ void scan_chunks(const int* __restrict__ chunkSum, int nchunks, int* __restrict__ chunkOff) {
    if (threadIdx.x == 0 && blockIdx.x == 0) {
        int run = 0;
        for (int i = 0; i < nchunks; i++) { chunkOff[i] = run; run += chunkSum[i]; }
    }
}

// ---- Pass 2c: apply — write row_start[] (CSR offsets) and reset counts->cursors ----
__global__ void scan_apply(int* __restrict__ counts, int n, const int* __restrict__ chunkOff,
                           int* __restrict__ row_start, int E) {
    __shared__ int lds[256];
    __shared__ int tOff[256];
    int t = threadIdx.x;
    int base = blockIdx.x * SCAN_CHUNK + t * 8;
    int vals[8]; int s = 0;
#pragma unroll
    for (int i = 0; i < 8; i++) { int idx = base + i; vals[i] = (idx < n) ? counts[idx] : 0; s += vals[i]; }
    lds[t] = s; __syncthreads();
    if (t == 0) { int run = 0; for (int i = 0; i < 256; i++) { tOff[i] = run; run += lds[i]; } }
    __syncthreads();
    int run = chunkOff[blockIdx.x] + tOff[t];
#pragma unroll
    for (int i = 0; i < 8; i++) {
        int idx = base + i;
        if (idx < n) { row_start[idx] = run; counts[idx] = run; run += vals[i]; }
    }
    if (blockIdx.x == 0 && t == 0) row_start[n] = E;
}

// ---- Pass 3: scatter edges into CSR order as (col, val) pairs ----
__global__ void scatter_kernel(const int* __restrict__ rows, const int* __restrict__ cols,
                               const float* __restrict__ vals, int E,
                               int* __restrict__ cur, int2* __restrict__ sorted) {
    int e = blockIdx.x * blockDim.x + threadIdx.x;
    if (e < E) {
        int r = rows[e];
        int pos = atomicAdd(&cur[r], 1);
        sorted[pos] = make_int2(cols[e], __float_as_int(vals[e]));
    }
}

// ---- SpMM pull-mode: 16 threads per row, float4 per thread; fused acc update ----
// MODE 0: y = A*x;  acc = x[r] + y        (layer 1, acc init fused)
// MODE 1: y = A*x;  acc += y              (layers 2,3)
// MODE 2: acc = (acc + A*x) * 0.2         (layer 4, mean fused, no y write)
template <int MODE>
__global__ __launch_bounds__(256) void spmm_kernel(const int2* __restrict__ sorted,
                                                   const int* __restrict__ row_start,
                                                   const float* __restrict__ x,
                                                   float* __restrict__ y,
                                                   float* __restrict__ acc) {
    int gid = blockIdx.x * blockDim.x + threadIdx.x;
    int r = gid >> 4;
    if (r >= N_NODES) return;
    int j = (gid & 15) << 2;
    int e = row_start[r], eend = row_start[r + 1];
    float4 a = make_float4(0.f, 0.f, 0.f, 0.f);
    for (; e < eend; ++e) {
        int2 cv = sorted[e];                       // all 16 lanes same addr -> L1 broadcast
        const float4 xv = *(const float4*)(x + (cv.x << 6) + j);
        float v = __int_as_float(cv.y);
        a.x = fmaf(v, xv.x, a.x);
        a.y = fmaf(v, xv.y, a.y);
        a.z = fmaf(v, xv.z, a.z);
        a.w = fmaf(v, xv.w, a.w);
    }
    int o = (r << 6) + j;
    if (MODE == 0) {
        const float4 x0 = *(const float4*)(x + o);
        *(float4*)(y + o) = a;
        *(float4*)(acc + o) = make_float4(x0.x + a.x, x0.y + a.y, x0.z + a.z, x0.w + a.w);
    } else if (MODE == 1) {
        *(float4*)(y + o) = a;
        float4 c = *(const float4*)(acc + o);
        *(float4*)(acc + o) = make_float4(c.x + a.x, c.y + a.y, c.z + a.z, c.w + a.w);
    } else {
        float4 c = *(const float4*)(acc + o);
        const float s = 0.2f;
        *(float4*)(acc + o) = make_float4((c.x + a.x) * s, (c.y + a.y) * s,
                                          (c.z + a.z) * s, (c.w + a.w) * s);
    }
}

extern "C" void kernel_launch(void* const* d_in, const int* in_sizes, int n_in,
                              void* d_out, int out_size, void* d_ws, size_t ws_size,
                              hipStream_t stream) {
    const float* embeds = (const float*)d_in[0];
    const int*   rows   = (const int*)d_in[1];
    const int*   cols   = (const int*)d_in[2];
    const float* vals   = (const float*)d_in[3];
    float* acc = (float*)d_out;
    const int E = in_sizes[1];
    const int N = in_sizes[0] / DIM;   // 200000

    // workspace carve-out (~156 MB)
    char* ws = (char*)d_ws;
    size_t off = 0;
    auto alloc = [&](size_t bytes) -> char* {
        char* p = ws + off;
        off = (off + bytes + 255) & ~(size_t)255;
        return p;
    };
    int*  cur       = (int*)alloc((size_t)N * 4);          // degree counts -> cursors
    int*  row_start = (int*)alloc((size_t)(N + 1) * 4);
    int*  chunkSum  = (int*)alloc(1024 * 4);
    int*  chunkOff  = (int*)alloc(1024 * 4);
    int2* sorted    = (int2*)alloc((size_t)E * 8);         // 51.2 MB
    float* x1       = (float*)alloc((size_t)N * DIM * 4);  // 51.2 MB
    float* x2       = (float*)alloc((size_t)N * DIM * 4);  // 51.2 MB

    hipMemsetAsync(cur, 0, (size_t)N * 4, stream);

    int eb = (E + 255) / 256;
    hist_kernel<<<eb, 256, 0, stream>>>(rows, E, cur);

    int nchunks = (N + SCAN_CHUNK - 1) / SCAN_CHUNK;   // 98
    scan_partial<<<nchunks, 256, 0, stream>>>(cur, N, chunkSum);
    scan_chunks<<<1, 64, 0, stream>>>(chunkSum, nchunks, chunkOff);
    scan_apply<<<nchunks, 256, 0, stream>>>(cur, N, chunkOff, row_start, E);

    scatter_kernel<<<eb, 256, 0, stream>>>(rows, cols, vals, E, cur, sorted);

    int sb = (N * 16 + 255) / 256;   // 16 threads per row
    spmm_kernel<0><<<sb, 256, 0, stream>>>(sorted, row_start, embeds, x1, acc);
    spmm_kernel<1><<<sb, 256, 0, stream>>>(sorted, row_start, x1, x2, acc);
    spmm_kernel<1><<<sb, 256, 0, stream>>>(sorted, row_start, x2, x1, acc);
    spmm_kernel<2><<<sb, 256, 0, stream>>>(sorted, row_start, x1, x2, acc);
}

// Round 2
// 1348.136 us; speedup vs baseline: 1.3694x; 1.3694x over previous
//
#include <hip/hip_runtime.h>

#define N_NODES 200000
#define DIM 64
#define BSHIFT 9                       // 512 rows per bucket
#define NB 391                         // ceil(200000 / 512)
#define NB_PAD 512
#define CHUNK 4096                     // edges per bucket_scatter block

// ---- Pass A: bucket histogram (LDS-staged) ----
__global__ __launch_bounds__(256) void bucket_hist(const int* __restrict__ rows, int E,
                                                   int* __restrict__ bcnt) {
    __shared__ int h[NB_PAD];
    for (int i = threadIdx.x; i < NB_PAD; i += 256) h[i] = 0;
    __syncthreads();
    int stride = gridDim.x * blockDim.x;
    for (int e = blockIdx.x * blockDim.x + threadIdx.x; e < E; e += stride)
        atomicAdd(&h[rows[e] >> BSHIFT], 1);
    __syncthreads();
    for (int i = threadIdx.x; i < NB; i += 256)
        if (h[i]) atomicAdd(&bcnt[i], h[i]);
}

// ---- Pass B: exclusive scan of 391 bucket counts (trivial) ----
__global__ void bucket_scan(const int* __restrict__ bcnt, int* __restrict__ bbase,
                            int* __restrict__ bcur) {
    if (threadIdx.x == 0 && blockIdx.x == 0) {
        int run = 0;
        for (int i = 0; i < NB; i++) { bbase[i] = run; bcur[i] = run; run += bcnt[i]; }
        bbase[NB] = run;
    }
}

// ---- Pass C: chunked scatter into bucket-grouped tmp, LDS-staged coalesced writes ----
// tmp[e] = ( (row_local<<18) | col , bits(val) )   [col < 2^18, row_local < 2^9]
__global__ __launch_bounds__(256) void bucket_scatter(const int* __restrict__ rows,
                                                      const int* __restrict__ cols,
                                                      const float* __restrict__ vals, int E,
                                                      int* __restrict__ bcur,
                                                      int2* __restrict__ tmp) {
    __shared__ int h[NB_PAD];
    __shared__ int incl[NB_PAD];
    __shared__ int sbuf[NB_PAD];
    __shared__ int fix[NB_PAD];
    __shared__ int cur2[NB_PAD];
    __shared__ int2 stage[CHUNK];
    __shared__ unsigned short sbkt[CHUNK];
    const int base = blockIdx.x * CHUNK;
    const int count = min(CHUNK, E - base);
    const int t = threadIdx.x;

    for (int i = t; i < NB_PAD; i += 256) h[i] = 0;
    __syncthreads();
    // phase 1: block-local bucket counts
    for (int i = t; i < count; i += 256)
        atomicAdd(&h[rows[base + i] >> BSHIFT], 1);
    __syncthreads();
    // phase 2: Hillis-Steele inclusive scan of h (512 elems, 2 per thread)
    for (int i = t; i < NB_PAD; i += 256) incl[i] = h[i];
    __syncthreads();
    for (int off = 1; off < NB_PAD; off <<= 1) {
        for (int i = t; i < NB_PAD; i += 256)
            sbuf[i] = incl[i] + ((i >= off) ? incl[i - off] : 0);
        __syncthreads();
        for (int i = t; i < NB_PAD; i += 256) incl[i] = sbuf[i];
        __syncthreads();
    }
    // reserve global runs; fix[b] maps staged slot -> global position
    for (int i = t; i < NB; i += 256) {
        int excl = incl[i] - h[i];
        int g = h[i] ? atomicAdd(&bcur[i], h[i]) : 0;
        fix[i] = g - excl;
        cur2[i] = excl;
    }
    __syncthreads();
    // phase 3: rank + stage in LDS grouped by bucket
    for (int i = t; i < count; i += 256) {
        int r = rows[base + i];
        int b = r >> BSHIFT;
        int slot = atomicAdd(&cur2[b], 1);
        int key = ((r & ((1 << BSHIFT) - 1)) << 18) | cols[base + i];
        stage[slot] = make_int2(key, __float_as_int(vals[base + i]));
        sbkt[slot] = (unsigned short)b;
    }
    __syncthreads();
    // phase 4: contiguous-run writes (coalesced at issue time)
    for (int s = t; s < count; s += 256)
        tmp[s + fix[sbkt[s]]] = stage[s];
}

// ---- Pass D: per-bucket counting sort by row + row_start emission ----
__global__ __launch_bounds__(256) void bucket_sort(const int2* __restrict__ tmp,
                                                   const int* __restrict__ bbase,
                                                   int2* __restrict__ sorted,
                                                   int* __restrict__ row_start) {
    __shared__ int h[NB_PAD];      // per-row counters -> exclusive offsets -> cursors
    __shared__ int sums[256];
    const int b = blockIdx.x;
    const int s0 = bbase[b], s1 = bbase[b + 1];
    const int t = threadIdx.x;
    h[t] = 0; h[t + 256] = 0;
    __syncthreads();
    for (int e = s0 + t; e < s1; e += 256)
        atomicAdd(&h[tmp[e].x >> 18], 1);
    __syncthreads();
    // exclusive scan of 512 counters: pairwise + serial scan of 256 partials
    int a0 = h[2 * t], a1 = h[2 * t + 1];
    sums[t] = a0 + a1;
    __syncthreads();
    if (t == 0) {
        int run = 0;
        for (int i = 0; i < 256; i++) { int v = sums[i]; sums[i] = run; run += v; }
    }
    __syncthreads();
    int e0 = sums[t];
    h[2 * t] = e0;
    h[2 * t + 1] = e0 + a0;
    __syncthreads();
    // row_start for this bucket's rows
    int rbase = b << BSHIFT;
    for (int r = t; r < (1 << BSHIFT); r += 256) {
        int row = rbase + r;
        if (row < N_NODES) row_start[row] = s0 + h[r];
    }
    if (b == NB - 1 && t == 0) row_start[N_NODES] = s1;   // s1 == E for last bucket
    __syncthreads();
    // cursor pass: scattered 8B writes within a ~131KB region -> L2-resident
    for (int e = s0 + t; e < s1; e += 256) {
        int2 kv = tmp[e];
        int r = kv.x >> 18;
        int rank = atomicAdd(&h[r], 1);
        sorted[s0 + rank] = make_int2(kv.x & 0x3FFFF, kv.y);
    }
}

// ---- SpMM pull-mode: 16 threads per row, float4 per thread; fused acc update ----
// MODE 0: y = A*x;  acc = x[r] + y        (layer 1, acc init fused)
// MODE 1: y = A*x;  acc += y              (layers 2,3)
// MODE 2: acc = (acc + A*x) * 0.2         (layer 4, mean fused, no y write)
template <int MODE>
__global__ __launch_bounds__(256) void spmm_kernel(const int2* __restrict__ sorted,
                                                   const int* __restrict__ row_start,
                                                   const float* __restrict__ x,
                                                   float* __restrict__ y,
                                                   float* __restrict__ acc) {
    int gid = blockIdx.x * blockDim.x + threadIdx.x;
    int r = gid >> 4;
    if (r >= N_NODES) return;
    int j = (gid & 15) << 2;
    int e = row_start[r], eend = row_start[r + 1];
    float4 a = make_float4(0.f, 0.f, 0.f, 0.f);
    for (; e < eend; ++e) {
        int2 cv = sorted[e];
        const float4 xv = *(const float4*)(x + (cv.x << 6) + j);
        float v = __int_as_float(cv.y);
        a.x = fmaf(v, xv.x, a.x);
        a.y = fmaf(v, xv.y, a.y);
        a.z = fmaf(v, xv.z, a.z);
        a.w = fmaf(v, xv.w, a.w);
    }
    int o = (r << 6) + j;
    if (MODE == 0) {
        const float4 x0 = *(const float4*)(x + o);
        *(float4*)(y + o) = a;
        *(float4*)(acc + o) = make_float4(x0.x + a.x, x0.y + a.y, x0.z + a.z, x0.w + a.w);
    } else if (MODE == 1) {
        *(float4*)(y + o) = a;
        float4 c = *(const float4*)(acc + o);
        *(float4*)(acc + o) = make_float4(c.x + a.x, c.y + a.y, c.z + a.z, c.w + a.w);
    } else {
        float4 c = *(const float4*)(acc + o);
        const float s = 0.2f;
        *(float4*)(acc + o) = make_float4((c.x + a.x) * s, (c.y + a.y) * s,
                                          (c.z + a.z) * s, (c.w + a.w) * s);
    }
}

extern "C" void kernel_launch(void* const* d_in, const int* in_sizes, int n_in,
                              void* d_out, int out_size, void* d_ws, size_t ws_size,
                              hipStream_t stream) {
    const float* embeds = (const float*)d_in[0];
    const int*   rows   = (const int*)d_in[1];
    const int*   cols   = (const int*)d_in[2];
    const float* vals   = (const float*)d_in[3];
    float* acc = (float*)d_out;
    const int E = in_sizes[1];

    // workspace carve-out (~156 MB); tmp aliases x1 (tmp dead before spmm<0> writes x1)
    char* ws = (char*)d_ws;
    size_t off = 0;
    auto alloc = [&](size_t bytes) -> char* {
        char* p = ws + off;
        off = (off + bytes + 255) & ~(size_t)255;
        return p;
    };
    int*   bcnt      = (int*)alloc((size_t)NB * 4);
    int*   bbase     = (int*)alloc((size_t)(NB + 1) * 4);
    int*   bcur      = (int*)alloc((size_t)NB * 4);
    int*   row_start = (int*)alloc((size_t)(N_NODES + 1) * 4);
    int2*  sorted    = (int2*)alloc((size_t)E * 8);                 // 51.2 MB
    float* x1        = (float*)alloc((size_t)N_NODES * DIM * 4);    // 51.2 MB (aliased by tmp)
    float* x2        = (float*)alloc((size_t)N_NODES * DIM * 4);    // 51.2 MB
    int2*  tmp       = (int2*)x1;

    hipMemsetAsync(bcnt, 0, (size_t)NB * 4, stream);

    bucket_hist<<<512, 256, 0, stream>>>(rows, E, bcnt);
    bucket_scan<<<1, 64, 0, stream>>>(bcnt, bbase, bcur);
    bucket_scatter<<<(E + CHUNK - 1) / CHUNK, 256, 0, stream>>>(rows, cols, vals, E, bcur, tmp);
    bucket_sort<<<NB, 256, 0, stream>>>(tmp, bbase, sorted, row_start);

    int sb = (N_NODES * 16 + 255) / 256;   // 16 threads per row
    spmm_kernel<0><<<sb, 256, 0, stream>>>(sorted, row_start, embeds, x1, acc);
    spmm_kernel<1><<<sb, 256, 0, stream>>>(sorted, row_start, x1, x2, acc);
    spmm_kernel<1><<<sb, 256, 0, stream>>>(sorted, row_start, x2, x1, acc);
    spmm_kernel<2><<<sb, 256, 0, stream>>>(sorted, row_start, x1, x2, acc);
}

// Round 3
// 1310.092 us; speedup vs baseline: 1.4092x; 1.0290x over previous
//
#include <hip/hip_runtime.h>

#define N_NODES 200000
#define DIM 64
#define BSHIFT 9                       // 512 rows per bucket
#define NB 391                         // ceil(200000 / 512)
#define NB_PAD 512
#define CHUNK 4096                     // edges per bucket_scatter block

// ---- Pass A: bucket histogram (LDS-staged) ----
__global__ __launch_bounds__(256) void bucket_hist(const int* __restrict__ rows, int E,
                                                   int* __restrict__ bcnt) {
    __shared__ int h[NB_PAD];
    for (int i = threadIdx.x; i < NB_PAD; i += 256) h[i] = 0;
    __syncthreads();
    int stride = gridDim.x * blockDim.x;
    for (int e = blockIdx.x * blockDim.x + threadIdx.x; e < E; e += stride)
        atomicAdd(&h[rows[e] >> BSHIFT], 1);
    __syncthreads();
    for (int i = threadIdx.x; i < NB; i += 256)
        if (h[i]) atomicAdd(&bcnt[i], h[i]);
}

// ---- Pass B: exclusive scan of 391 bucket counts (trivial) ----
__global__ void bucket_scan(const int* __restrict__ bcnt, int* __restrict__ bbase,
                            int* __restrict__ bcur) {
    if (threadIdx.x == 0 && blockIdx.x == 0) {
        int run = 0;
        for (int i = 0; i < NB; i++) { bbase[i] = run; bcur[i] = run; run += bcnt[i]; }
        bbase[NB] = run;
    }
}

// ---- Pass C: chunked scatter into bucket-grouped tmp, LDS-staged coalesced writes ----
// tmp[e] = ( (row_local<<18) | col , bits(val) )   [col < 2^18, row_local < 2^9]
__global__ __launch_bounds__(256) void bucket_scatter(const int* __restrict__ rows,
                                                      const int* __restrict__ cols,
                                                      const float* __restrict__ vals, int E,
                                                      int* __restrict__ bcur,
                                                      int2* __restrict__ tmp) {
    __shared__ int h[NB_PAD];
    __shared__ int incl[NB_PAD];
    __shared__ int sbuf[NB_PAD];
    __shared__ int fix[NB_PAD];
    __shared__ int cur2[NB_PAD];
    __shared__ int2 stage[CHUNK];
    __shared__ unsigned short sbkt[CHUNK];
    const int base = blockIdx.x * CHUNK;
    const int count = min(CHUNK, E - base);
    const int t = threadIdx.x;

    for (int i = t; i < NB_PAD; i += 256) h[i] = 0;
    __syncthreads();
    // phase 1: block-local bucket counts
    for (int i = t; i < count; i += 256)
        atomicAdd(&h[rows[base + i] >> BSHIFT], 1);
    __syncthreads();
    // phase 2: Hillis-Steele inclusive scan of h (512 elems)
    for (int i = t; i < NB_PAD; i += 256) incl[i] = h[i];
    __syncthreads();
    for (int off = 1; off < NB_PAD; off <<= 1) {
        for (int i = t; i < NB_PAD; i += 256)
            sbuf[i] = incl[i] + ((i >= off) ? incl[i - off] : 0);
        __syncthreads();
        for (int i = t; i < NB_PAD; i += 256) incl[i] = sbuf[i];
        __syncthreads();
    }
    // reserve global runs; fix[b] maps staged slot -> global position
    for (int i = t; i < NB; i += 256) {
        int excl = incl[i] - h[i];
        int g = h[i] ? atomicAdd(&bcur[i], h[i]) : 0;
        fix[i] = g - excl;
        cur2[i] = excl;
    }
    __syncthreads();
    // phase 3: rank + stage in LDS grouped by bucket
    for (int i = t; i < count; i += 256) {
        int r = rows[base + i];
        int b = r >> BSHIFT;
        int slot = atomicAdd(&cur2[b], 1);
        int key = ((r & ((1 << BSHIFT) - 1)) << 18) | cols[base + i];
        stage[slot] = make_int2(key, __float_as_int(vals[base + i]));
        sbkt[slot] = (unsigned short)b;
    }
    __syncthreads();
    // phase 4: contiguous-run writes (coalesced at issue time)
    for (int s = t; s < count; s += 256)
        tmp[s + fix[sbkt[s]]] = stage[s];
}

// ---- Pass D: per-bucket counting sort by row + row_start emission ----
__global__ __launch_bounds__(256) void bucket_sort(const int2* __restrict__ tmp,
                                                   const int* __restrict__ bbase,
                                                   int2* __restrict__ sorted,
                                                   int* __restrict__ row_start) {
    __shared__ int h[NB_PAD];      // per-row counters -> exclusive offsets -> cursors
    __shared__ int sums[256];
    const int b = blockIdx.x;
    const int s0 = bbase[b], s1 = bbase[b + 1];
    const int t = threadIdx.x;
    h[t] = 0; h[t + 256] = 0;
    __syncthreads();
    for (int e = s0 + t; e < s1; e += 256)
        atomicAdd(&h[tmp[e].x >> 18], 1);
    __syncthreads();
    // exclusive scan of 512 counters: pairwise + serial scan of 256 partials
    int a0 = h[2 * t], a1 = h[2 * t + 1];
    sums[t] = a0 + a1;
    __syncthreads();
    if (t == 0) {
        int run = 0;
        for (int i = 0; i < 256; i++) { int v = sums[i]; sums[i] = run; run += v; }
    }
    __syncthreads();
    int e0 = sums[t];
    h[2 * t] = e0;
    h[2 * t + 1] = e0 + a0;
    __syncthreads();
    // row_start for this bucket's rows
    int rbase = b << BSHIFT;
    for (int r = t; r < (1 << BSHIFT); r += 256) {
        int row = rbase + r;
        if (row < N_NODES) row_start[row] = s0 + h[r];
    }
    if (b == NB - 1 && t == 0) row_start[N_NODES] = s1;   // s1 == E for last bucket
    __syncthreads();
    // cursor pass: scattered 8B writes within a ~131KB region -> L2-resident
    for (int e = s0 + t; e < s1; e += 256) {
        int2 kv = tmp[e];
        int r = kv.x >> 18;
        int rank = atomicAdd(&h[r], 1);
        sorted[s0 + rank] = make_int2(kv.x & 0x3FFFF, kv.y);
    }
}

// ---- SpMM pull-mode: 16 threads per row, float4 per thread, 4-edge unroll ----
// The 4 sorted[] loads are one contiguous 32B quad; the 4 x-gathers are
// independent -> 4 outstanding 256B gathers per 16-lane group (MLP x4).
// MODE 0: y = A*x;  acc = x[r] + y        (layer 1, acc init fused)
// MODE 1: y = A*x;  acc += y              (layers 2,3)
// MODE 2: acc = (acc + A*x) * 0.2         (layer 4, mean fused, no y write)
template <int MODE>
__global__ __launch_bounds__(256) void spmm_kernel(const int2* __restrict__ sorted,
                                                   const int* __restrict__ row_start,
                                                   const float* __restrict__ x,
                                                   float* __restrict__ y,
                                                   float* __restrict__ acc) {
    int gid = blockIdx.x * blockDim.x + threadIdx.x;
    int r = gid >> 4;
    if (r >= N_NODES) return;
    int j = (gid & 15) << 2;
    int e = row_start[r], eend = row_start[r + 1];
    float4 a = make_float4(0.f, 0.f, 0.f, 0.f);
    for (; e + 4 <= eend; e += 4) {
        int2 c0 = sorted[e];
        int2 c1 = sorted[e + 1];
        int2 c2 = sorted[e + 2];
        int2 c3 = sorted[e + 3];
        const float4 x0 = *(const float4*)(x + (c0.x << 6) + j);
        const float4 x1 = *(const float4*)(x + (c1.x << 6) + j);
        const float4 x2 = *(const float4*)(x + (c2.x << 6) + j);
        const float4 x3 = *(const float4*)(x + (c3.x << 6) + j);
        float v0 = __int_as_float(c0.y), v1 = __int_as_float(c1.y);
        float v2 = __int_as_float(c2.y), v3 = __int_as_float(c3.y);
        a.x = fmaf(v0, x0.x, a.x); a.y = fmaf(v0, x0.y, a.y);
        a.z = fmaf(v0, x0.z, a.z); a.w = fmaf(v0, x0.w, a.w);
        a.x = fmaf(v1, x1.x, a.x); a.y = fmaf(v1, x1.y, a.y);
        a.z = fmaf(v1, x1.z, a.z); a.w = fmaf(v1, x1.w, a.w);
        a.x = fmaf(v2, x2.x, a.x); a.y = fmaf(v2, x2.y, a.y);
        a.z = fmaf(v2, x2.z, a.z); a.w = fmaf(v2, x2.w, a.w);
        a.x = fmaf(v3, x3.x, a.x); a.y = fmaf(v3, x3.y, a.y);
        a.z = fmaf(v3, x3.z, a.z); a.w = fmaf(v3, x3.w, a.w);
    }
    for (; e < eend; ++e) {
        int2 cv = sorted[e];
        const float4 xv = *(const float4*)(x + (cv.x << 6) + j);
        float v = __int_as_float(cv.y);
        a.x = fmaf(v, xv.x, a.x);
        a.y = fmaf(v, xv.y, a.y);
        a.z = fmaf(v, xv.z, a.z);
        a.w = fmaf(v, xv.w, a.w);
    }
    int o = (r << 6) + j;
    if (MODE == 0) {
        const float4 x0 = *(const float4*)(x + o);
        *(float4*)(y + o) = a;
        *(float4*)(acc + o) = make_float4(x0.x + a.x, x0.y + a.y, x0.z + a.z, x0.w + a.w);
    } else if (MODE == 1) {
        *(float4*)(y + o) = a;
        float4 c = *(const float4*)(acc + o);
        *(float4*)(acc + o) = make_float4(c.x + a.x, c.y + a.y, c.z + a.z, c.w + a.w);
    } else {
        float4 c = *(const float4*)(acc + o);
        const float s = 0.2f;
        *(float4*)(acc + o) = make_float4((c.x + a.x) * s, (c.y + a.y) * s,
                                          (c.z + a.z) * s, (c.w + a.w) * s);
    }
}

extern "C" void kernel_launch(void* const* d_in, const int* in_sizes, int n_in,
                              void* d_out, int out_size, void* d_ws, size_t ws_size,
                              hipStream_t stream) {
    const float* embeds = (const float*)d_in[0];
    const int*   rows   = (const int*)d_in[1];
    const int*   cols   = (const int*)d_in[2];
    const float* vals   = (const float*)d_in[3];
    float* acc = (float*)d_out;
    const int E = in_sizes[1];

    // workspace carve-out (~156 MB); tmp aliases x1 (tmp dead before spmm<0> writes x1)
    char* ws = (char*)d_ws;
    size_t off = 0;
    auto alloc = [&](size_t bytes) -> char* {
        char* p = ws + off;
        off = (off + bytes + 255) & ~(size_t)255;
        return p;
    };
    int*   bcnt      = (int*)alloc((size_t)NB * 4);
    int*   bbase     = (int*)alloc((size_t)(NB + 1) * 4);
    int*   bcur      = (int*)alloc((size_t)NB * 4);
    int*   row_start = (int*)alloc((size_t)(N_NODES + 1) * 4);
    int2*  sorted    = (int2*)alloc((size_t)E * 8);                 // 51.2 MB
    float* x1        = (float*)alloc((size_t)N_NODES * DIM * 4);    // 51.2 MB (aliased by tmp)
    float* x2        = (float*)alloc((size_t)N_NODES * DIM * 4);    // 51.2 MB
    int2*  tmp       = (int2*)x1;

    hipMemsetAsync(bcnt, 0, (size_t)NB * 4, stream);

    bucket_hist<<<512, 256, 0, stream>>>(rows, E, bcnt);
    bucket_scan<<<1, 64, 0, stream>>>(bcnt, bbase, bcur);
    bucket_scatter<<<(E + CHUNK - 1) / CHUNK, 256, 0, stream>>>(rows, cols, vals, E, bcur, tmp);
    bucket_sort<<<NB, 256, 0, stream>>>(tmp, bbase, sorted, row_start);

    int sb = (N_NODES * 16 + 255) / 256;   // 16 threads per row
    spmm_kernel<0><<<sb, 256, 0, stream>>>(sorted, row_start, embeds, x1, acc);
    spmm_kernel<1><<<sb, 256, 0, stream>>>(sorted, row_start, x1, x2, acc);
    spmm_kernel<1><<<sb, 256, 0, stream>>>(sorted, row_start, x2, x1, acc);
    spmm_kernel<2><<<sb, 256, 0, stream>>>(sorted, row_start, x1, x2, acc);
}

// Round 4
// 887.931 us; speedup vs baseline: 2.0792x; 1.4754x over previous
//
#include <hip/hip_runtime.h>

#define N_NODES 200000
#define DIM 64
#define BSHIFT 9                       // 512 rows per bucket
#define NB 391                         // ceil(200000 / 512)
#define NB_PAD 512
#define CHUNK 4096                     // edges per bucket_scatter block

__device__ __forceinline__ float bf2f(unsigned short u) {
    return __uint_as_float(((unsigned int)u) << 16);
}
__device__ __forceinline__ unsigned short f2bf(float f) {
    unsigned int u = __float_as_uint(f);
    u += 0x7FFFu + ((u >> 16) & 1u);   // round-to-nearest-even
    return (unsigned short)(u >> 16);
}

// ---- Pass A: bucket histogram (LDS-staged) ----
__global__ __launch_bounds__(256) void bucket_hist(const int* __restrict__ rows, int E,
                                                   int* __restrict__ bcnt) {
    __shared__ int h[NB_PAD];
    for (int i = threadIdx.x; i < NB_PAD; i += 256) h[i] = 0;
    __syncthreads();
    int stride = gridDim.x * blockDim.x;
    for (int e = blockIdx.x * blockDim.x + threadIdx.x; e < E; e += stride)
        atomicAdd(&h[rows[e] >> BSHIFT], 1);
    __syncthreads();
    for (int i = threadIdx.x; i < NB; i += 256)
        if (h[i]) atomicAdd(&bcnt[i], h[i]);
}

// ---- Pass B: exclusive scan of 391 bucket counts ----
__global__ void bucket_scan(const int* __restrict__ bcnt, int* __restrict__ bbase,
                            int* __restrict__ bcur) {
    if (threadIdx.x == 0 && blockIdx.x == 0) {
        int run = 0;
        for (int i = 0; i < NB; i++) { bbase[i] = run; bcur[i] = run; run += bcnt[i]; }
        bbase[NB] = run;
    }
}

// ---- Pass C: chunked scatter into bucket-grouped tmp, LDS-staged coalesced writes ----
__global__ __launch_bounds__(256) void bucket_scatter(const int* __restrict__ rows,
                                                      const int* __restrict__ cols,
                                                      const float* __restrict__ vals, int E,
                                                      int* __restrict__ bcur,
                                                      int2* __restrict__ tmp) {
    __shared__ int h[NB_PAD];
    __shared__ int incl[NB_PAD];
    __shared__ int sbuf[NB_PAD];
    __shared__ int fix[NB_PAD];
    __shared__ int cur2[NB_PAD];
    __shared__ int2 stage[CHUNK];
    __shared__ unsigned short sbkt[CHUNK];
    const int base = blockIdx.x * CHUNK;
    const int count = min(CHUNK, E - base);
    const int t = threadIdx.x;

    for (int i = t; i < NB_PAD; i += 256) h[i] = 0;
    __syncthreads();
    for (int i = t; i < count; i += 256)
        atomicAdd(&h[rows[base + i] >> BSHIFT], 1);
    __syncthreads();
    for (int i = t; i < NB_PAD; i += 256) incl[i] = h[i];
    __syncthreads();
    for (int off = 1; off < NB_PAD; off <<= 1) {
        for (int i = t; i < NB_PAD; i += 256)
            sbuf[i] = incl[i] + ((i >= off) ? incl[i - off] : 0);
        __syncthreads();
        for (int i = t; i < NB_PAD; i += 256) incl[i] = sbuf[i];
        __syncthreads();
    }
    for (int i = t; i < NB; i += 256) {
        int excl = incl[i] - h[i];
        int g = h[i] ? atomicAdd(&bcur[i], h[i]) : 0;
        fix[i] = g - excl;
        cur2[i] = excl;
    }
    __syncthreads();
    for (int i = t; i < count; i += 256) {
        int r = rows[base + i];
        int b = r >> BSHIFT;
        int slot = atomicAdd(&cur2[b], 1);
        int key = ((r & ((1 << BSHIFT) - 1)) << 18) | cols[base + i];
        stage[slot] = make_int2(key, __float_as_int(vals[base + i]));
        sbkt[slot] = (unsigned short)b;
    }
    __syncthreads();
    for (int s = t; s < count; s += 256)
        tmp[s + fix[sbkt[s]]] = stage[s];
}

// ---- Pass D: per-bucket counting sort by row + row_start emission ----
__global__ __launch_bounds__(256) void bucket_sort(const int2* __restrict__ tmp,
                                                   const int* __restrict__ bbase,
                                                   int2* __restrict__ sorted,
                                                   int* __restrict__ row_start) {
    __shared__ int h[NB_PAD];
    __shared__ int sums[256];
    const int b = blockIdx.x;
    const int s0 = bbase[b], s1 = bbase[b + 1];
    const int t = threadIdx.x;
    h[t] = 0; h[t + 256] = 0;
    __syncthreads();
    for (int e = s0 + t; e < s1; e += 256)
        atomicAdd(&h[tmp[e].x >> 18], 1);
    __syncthreads();
    int a0 = h[2 * t], a1 = h[2 * t + 1];
    sums[t] = a0 + a1;
    __syncthreads();
    if (t == 0) {
        int run = 0;
        for (int i = 0; i < 256; i++) { int v = sums[i]; sums[i] = run; run += v; }
    }
    __syncthreads();
    int e0 = sums[t];
    h[2 * t] = e0;
    h[2 * t + 1] = e0 + a0;
    __syncthreads();
    int rbase = b << BSHIFT;
    for (int r = t; r < (1 << BSHIFT); r += 256) {
        int row = rbase + r;
        if (row < N_NODES) row_start[row] = s0 + h[r];
    }
    if (b == NB - 1 && t == 0) row_start[N_NODES] = s1;
    __syncthreads();
    for (int e = s0 + t; e < s1; e += 256) {
        int2 kv = tmp[e];
        int r = kv.x >> 18;
        int rank = atomicAdd(&h[r], 1);
        sorted[s0 + rank] = make_int2(kv.x & 0x3FFFF, kv.y);
    }
}

// ---- fp32 -> bf16 convert (embeds -> xb0) ----
__global__ __launch_bounds__(256) void convert_kernel(const float* __restrict__ src,
                                                      unsigned short* __restrict__ dst, int n4) {
    int i = blockIdx.x * blockDim.x + threadIdx.x;
    if (i >= n4) return;
    float4 v = *(const float4*)(src + i * 4);
    ushort4 o;
    o.x = f2bf(v.x); o.y = f2bf(v.y); o.z = f2bf(v.z); o.w = f2bf(v.w);
    *(ushort4*)(dst + i * 4) = o;
}

// ---- SpMM pull-mode, bf16 gather: 16 threads/row, 4 feats (ushort4=8B)/thread ----
// One 128B line per edge-gather (vs 2 for fp32). Accumulate fp32.
// MODE 0: y_bf = A*xb;  acc = embeds[r] + (A*xb)      (layer 1)
// MODE 1: y_bf = A*xb;  acc += A*xb                    (layers 2,3)
// MODE 2: acc = (acc + A*xb) * 0.2                     (layer 4, no y)
template <int MODE>
__global__ __launch_bounds__(256) void spmm_kernel(const int2* __restrict__ sorted,
                                                   const int* __restrict__ row_start,
                                                   const unsigned short* __restrict__ xb,
                                                   const float* __restrict__ embeds,
                                                   unsigned short* __restrict__ y,
                                                   float* __restrict__ acc) {
    int gid = blockIdx.x * blockDim.x + threadIdx.x;
    int r = gid >> 4;
    if (r >= N_NODES) return;
    int j = (gid & 15) << 2;
    int e = row_start[r], eend = row_start[r + 1];
    float4 a = make_float4(0.f, 0.f, 0.f, 0.f);
    for (; e + 4 <= eend; e += 4) {
        int2 c0 = sorted[e];
        int2 c1 = sorted[e + 1];
        int2 c2 = sorted[e + 2];
        int2 c3 = sorted[e + 3];
        ushort4 u0 = *(const ushort4*)(xb + (c0.x << 6) + j);
        ushort4 u1 = *(const ushort4*)(xb + (c1.x << 6) + j);
        ushort4 u2 = *(const ushort4*)(xb + (c2.x << 6) + j);
        ushort4 u3 = *(const ushort4*)(xb + (c3.x << 6) + j);
        float v0 = __int_as_float(c0.y), v1 = __int_as_float(c1.y);
        float v2 = __int_as_float(c2.y), v3 = __int_as_float(c3.y);
        a.x = fmaf(v0, bf2f(u0.x), a.x); a.y = fmaf(v0, bf2f(u0.y), a.y);
        a.z = fmaf(v0, bf2f(u0.z), a.z); a.w = fmaf(v0, bf2f(u0.w), a.w);
        a.x = fmaf(v1, bf2f(u1.x), a.x); a.y = fmaf(v1, bf2f(u1.y), a.y);
        a.z = fmaf(v1, bf2f(u1.z), a.z); a.w = fmaf(v1, bf2f(u1.w), a.w);
        a.x = fmaf(v2, bf2f(u2.x), a.x); a.y = fmaf(v2, bf2f(u2.y), a.y);
        a.z = fmaf(v2, bf2f(u2.z), a.z); a.w = fmaf(v2, bf2f(u2.w), a.w);
        a.x = fmaf(v3, bf2f(u3.x), a.x); a.y = fmaf(v3, bf2f(u3.y), a.y);
        a.z = fmaf(v3, bf2f(u3.z), a.z); a.w = fmaf(v3, bf2f(u3.w), a.w);
    }
    for (; e < eend; ++e) {
        int2 cv = sorted[e];
        ushort4 u = *(const ushort4*)(xb + (cv.x << 6) + j);
        float v = __int_as_float(cv.y);
        a.x = fmaf(v, bf2f(u.x), a.x);
        a.y = fmaf(v, bf2f(u.y), a.y);
        a.z = fmaf(v, bf2f(u.z), a.z);
        a.w = fmaf(v, bf2f(u.w), a.w);
    }
    int o = (r << 6) + j;
    if (MODE == 0) {
        ushort4 yo; yo.x = f2bf(a.x); yo.y = f2bf(a.y); yo.z = f2bf(a.z); yo.w = f2bf(a.w);
        *(ushort4*)(y + o) = yo;
        const float4 x0 = *(const float4*)(embeds + o);
        *(float4*)(acc + o) = make_float4(x0.x + a.x, x0.y + a.y, x0.z + a.z, x0.w + a.w);
    } else if (MODE == 1) {
        ushort4 yo; yo.x = f2bf(a.x); yo.y = f2bf(a.y); yo.z = f2bf(a.z); yo.w = f2bf(a.w);
        *(ushort4*)(y + o) = yo;
        float4 c = *(const float4*)(acc + o);
        *(float4*)(acc + o) = make_float4(c.x + a.x, c.y + a.y, c.z + a.z, c.w + a.w);
    } else {
        float4 c = *(const float4*)(acc + o);
        const float s = 0.2f;
        *(float4*)(acc + o) = make_float4((c.x + a.x) * s, (c.y + a.y) * s,
                                          (c.z + a.z) * s, (c.w + a.w) * s);
    }
}

extern "C" void kernel_launch(void* const* d_in, const int* in_sizes, int n_in,
                              void* d_out, int out_size, void* d_ws, size_t ws_size,
                              hipStream_t stream) {
    const float* embeds = (const float*)d_in[0];
    const int*   rows   = (const int*)d_in[1];
    const int*   cols   = (const int*)d_in[2];
    const float* vals   = (const float*)d_in[3];
    float* acc = (float*)d_out;
    const int E = in_sizes[1];

    // workspace carve-out; xb0/xb1 alias tmp's region (tmp dead after bucket_sort,
    // convert runs after bucket_sort)
    char* ws = (char*)d_ws;
    size_t off = 0;
    auto alloc = [&](size_t bytes) -> char* {
        char* p = ws + off;
        off = (off + bytes + 255) & ~(size_t)255;
        return p;
    };
    int*   bcnt      = (int*)alloc((size_t)NB * 4);
    int*   bbase     = (int*)alloc((size_t)(NB + 1) * 4);
    int*   bcur      = (int*)alloc((size_t)NB * 4);
    int*   row_start = (int*)alloc((size_t)(N_NODES + 1) * 4);
    int2*  sorted    = (int2*)alloc((size_t)E * 8);                         // 51.2 MB
    unsigned short* xb0 = (unsigned short*)alloc((size_t)N_NODES * DIM * 2); // 25.6 MB
    unsigned short* xb1 = (unsigned short*)alloc((size_t)N_NODES * DIM * 2); // 25.6 MB
    int2*  tmp       = (int2*)alloc((size_t)E * 8);                         // 51.2 MB

    hipMemsetAsync(bcnt, 0, (size_t)NB * 4, stream);

    bucket_hist<<<512, 256, 0, stream>>>(rows, E, bcnt);
    bucket_scan<<<1, 64, 0, stream>>>(bcnt, bbase, bcur);
    bucket_scatter<<<(E + CHUNK - 1) / CHUNK, 256, 0, stream>>>(rows, cols, vals, E, bcur, tmp);
    bucket_sort<<<NB, 256, 0, stream>>>(tmp, bbase, sorted, row_start);

    int n4 = N_NODES * DIM / 4;
    convert_kernel<<<(n4 + 255) / 256, 256, 0, stream>>>(embeds, xb0, n4);

    int sb = (N_NODES * 16 + 255) / 256;   // 16 threads per row
    spmm_kernel<0><<<sb, 256, 0, stream>>>(sorted, row_start, xb0, embeds, xb1, acc);
    spmm_kernel<1><<<sb, 256, 0, stream>>>(sorted, row_start, xb1, embeds, xb0, acc);
    spmm_kernel<1><<<sb, 256, 0, stream>>>(sorted, row_start, xb0, embeds, xb1, acc);
    spmm_kernel<2><<<sb, 256, 0, stream>>>(sorted, row_start, xb1, embeds, xb0, acc);
}